// Round 10
// baseline (36.177 us; speedup 1.0000x reference)
//
#include <hip/hip_runtime.h>

#define NVELL 1024

typedef float v2 __attribute__((ext_vector_type(2)));

__device__ __forceinline__ float rcp1(float x){ return __builtin_amdgcn_rcpf(x); }
__device__ __forceinline__ v2 bc(float x){ v2 r = {x, x}; return r; }
__device__ __forceinline__ v2 rcp2(v2 x){ v2 r = {rcp1(x.x), rcp1(x.y)}; return r; }

// 128-position ring: pos = half*64 + lane (half 0 = .x, half 1 = .y).
// seamL/seamR: fetch the triple at pos -/+ st, zero outside [0,128).
__device__ __forceinline__ v2 seamL(v2 p, int lane, int st){
  float sx = __shfl(p.x, (lane - st) & 63, 64);
  float sy = __shfl(p.y, (lane - st) & 63, 64);
  v2 r; r.x = (lane >= st) ? sx : 0.f; r.y = (lane >= st) ? sy : sx; return r;
}
__device__ __forceinline__ v2 seamR(v2 p, int lane, int st){
  float sx = __shfl(p.x, (lane + st) & 63, 64);
  float sy = __shfl(p.y, (lane + st) & 63, 64);
  v2 r; r.x = (lane + st <= 63) ? sx : sy; r.y = (lane + st <= 63) ? sy : 0.f; return r;
}

// ---- DPP wave-sum: row_shr 1,2,4,8 + row_bcast15 + row_bcast31, total in lane 63 ----
template<int CTRL>
__device__ __forceinline__ float dpp_add(float x) {
  float t = __int_as_float(__builtin_amdgcn_update_dpp(
      0, __float_as_int(x), CTRL, 0xf, 0xf, true));
  return x + t;
}
__device__ __forceinline__ float wavesum(float x) {
  x = dpp_add<0x111>(x);   // row_shr:1
  x = dpp_add<0x112>(x);   // row_shr:2
  x = dpp_add<0x114>(x);   // row_shr:4
  x = dpp_add<0x118>(x);   // row_shr:8
  x = dpp_add<0x142>(x);   // row_bcast15
  x = dpp_add<0x143>(x);   // row_bcast31
  return __int_as_float(__builtin_amdgcn_readlane(__float_as_int(x), 63));
}

__global__ __launch_bounds__(256, 6) void fp_step_kernel(
    const float* __restrict__ f, const float* __restrict__ v,
    const float* __restrict__ ve, const float* __restrict__ p_dv,
    const float* __restrict__ p_nu, const float* __restrict__ p_dt,
    float* __restrict__ out, int nrows)
{
  const int lane = threadIdx.x & 63;
  const int wid  = threadIdx.x >> 6;
  const int row  = blockIdx.x * 4 + wid;
  if (row >= nrows) return;

  const float dv   = *p_dv;
  const float nu   = *p_nu;
  const float dt   = *p_dt;
  const float vmin = ve[0];
  const int   cb   = lane * 8;          // base cell of .x block; .y block at cb+512

  // ---- load f: 8 cells of each half-row, packed {left, right} ----
  const float* fp = f + (size_t)row * NVELL + cb;
  v2 fr[8];
  {
    float4 A0 = reinterpret_cast<const float4*>(fp)[0];
    float4 A1 = reinterpret_cast<const float4*>(fp)[1];
    float4 B0 = reinterpret_cast<const float4*>(fp + 512)[0];
    float4 B1 = reinterpret_cast<const float4*>(fp + 512)[1];
    fr[0] = (v2){A0.x, B0.x}; fr[1] = (v2){A0.y, B0.y};
    fr[2] = (v2){A0.z, B0.z}; fr[3] = (v2){A0.w, B0.w};
    fr[4] = (v2){A1.x, B1.x}; fr[5] = (v2){A1.y, B1.y};
    fr[6] = (v2){A1.z, B1.z}; fr[7] = (v2){A1.w, B1.w};
  }

  const float half_off = 512.0f * dv;   // = 6.0 exactly
  const float vb0 = __builtin_fmaf((float)cb + 0.5f, dv, vmin);  // exact in f32

  // ---- moments: n, vbar, e_t (accumulate packed, reduce combined via DPP) ----
  v2 sf = bc(0.f), sfv = bc(0.f), sfv2 = bc(0.f);
  {
    v2 vt = (v2){vb0, vb0 + half_off};
    #pragma unroll
    for (int i = 0; i < 8; ++i) {
      v2 fv = fr[i] * vt;
      sf   += fr[i];
      sfv  += fv;
      sfv2 += fv * vt;
      vt   += bc(dv);
    }
  }
  const float Sf   = wavesum(sf.x + sf.y);
  const float Sfv  = wavesum(sfv.x + sfv.y);
  const float Sfv2 = wavesum(sfv2.x + sfv2.y);
  const float vbar = Sfv * rcp1(Sf);
  const float nnn  = Sf * dv;
  const float e_t  = dv * __builtin_fmaf(-vbar, Sfv, Sfv2);
  // Self-consistent beta fixed point collapses at f32 (validated R2/R8).
  const float beta = 0.5f * nnn * rcp1(e_t);

  // ---- scalar (wave-uniform) params ----
  const float Dd    = 0.5f * rcp1(beta);
  const float idv   = rcp1(dv);
  const float s     = dt * nu * idv;
  const float twobD = (beta + beta) * Dd;      // mirrors reference 2*beta*D
  const float wfac  = dv * (beta + beta);      // = dv/D up to rcp rounding
  const float kW    = twobD * wfac;            // w = kW*e + cW
  const float cWc   = -(kW * vbar);
  const float Rs    = Dd * (s * idv);          // s*De/dv (interior edges)

  // per-edge alpha/gamma: row i = (a,b,c) = (alpha_i, 1 - gamma_i - alpha_{i+1}, gamma_{i+1})
  // alpha = Rs*(w*delta - 1), gamma = Rs*(w*delta - w) - Rs
  // delta via Bernoulli series: 1/2 - w/12 + w^3/720 - w^5/30240
  auto edgeAG = [&](v2 e, v2 &al, v2 &ga) {
    v2 w  = bc(kW) * e + bc(cWc);
    v2 w2 = w * w;
    v2 p  = w2 * bc(-3.30687830e-5f) + bc(1.38888889e-3f);
    p     = w2 * p + bc(-8.33333333e-2f);
    v2 dl = w * p + bc(0.5f);
    v2 t  = w * dl;
    al = bc(Rs) * t - bc(Rs);
    ga = bc(Rs) * (t - w) - bc(Rs);
  };

  const float exl = __builtin_fmaf((float)cb, dv, vmin);   // edge 0 of .x block
  const v2 e0base = (v2){exl, exl + half_off};

  // ---- UP-sweep rows 1..6 (array-free):  x_i = Gu + Hu*x_{i+1} + Ku*x0 ----
  v2 Gu = bc(0.f), Hu = bc(0.f), Ku = bc(1.f);
  v2 e1a, e1g, e1d;
  {
    v2 ePos = e0base + bc(dv);           // edge 1
    v2 alL, gaL; edgeAG(ePos, alL, gaL);
    #pragma unroll
    for (int i = 1; i <= 6; ++i) {
      ePos += bc(dv);                    // edge i+1
      v2 alR, gaR; edgeAG(ePos, alR, gaR);
      v2 a = alL;
      v2 c = gaR;
      v2 b = bc(1.f) - gaL - alR;
      v2 r = rcp2(b + a * Hu);
      Gu = (fr[i] - a * Gu) * r;
      Hu = -(c) * r;
      Ku = -(a * Ku) * r;
      alL = alR; gaL = gaR;
    }
    // row 7 -> e1 ring equation (edge 8; global mask at lane63 .y)
    ePos += bc(dv);                      // edge 8
    v2 alR, gaR; edgeAG(ePos, alR, gaR);
    if (lane == 63) { alR.y = 0.f; gaR.y = 0.f; }
    v2 a7 = alL;
    v2 c7 = gaR;
    v2 b7 = bc(1.f) - gaL - alR;
    v2 rL = rcp2(b7 + a7 * Hu);
    e1a = (a7 * Ku) * rL;                // couples own FIRST
    e1g = c7 * rL;                       // couples next block's FIRST
    e1d = (fr[7] - a7 * Gu) * rL;
  }

  // ---- DOWN-sweep rows 6..1 (array-free):  x_i = Gd + Hd*x_{i-1} + Kd*x7 ----
  v2 Gd = bc(0.f), Hd = bc(0.f), Kd = bc(1.f);
  v2 e0a, e0g, e0d;
  {
    v2 ePos = e0base + bc(7.f * dv);     // edge 7
    v2 alR, gaR; edgeAG(ePos, alR, gaR);
    #pragma unroll
    for (int i = 6; i >= 1; --i) {
      ePos -= bc(dv);                    // edge i
      v2 alL, gaL; edgeAG(ePos, alL, gaL);
      v2 a = alL;
      v2 c = gaR;
      v2 b = bc(1.f) - gaL - alR;
      v2 r = rcp2(b + c * Hd);
      Gd = (fr[i] - c * Gd) * r;
      Hd = -(a) * r;
      Kd = -(c * Kd) * r;
      alR = alL; gaR = gaL;
    }
    // row 0 -> e0 ring equation (edge 0; global mask at lane0 .x)
    v2 ePos0 = e0base;
    v2 alL, gaL; edgeAG(ePos0, alL, gaL);
    if (lane == 0) { alL.x = 0.f; gaL.x = 0.f; }
    v2 a0 = alL;
    v2 c0 = gaR;
    v2 b0 = bc(1.f) - gaL - alR;
    v2 rF = rcp2(b0 + c0 * Hd);
    e0a = a0 * rF;                       // couples prev block's LAST
    e0g = (c0 * Kd) * rF;                // couples own LAST
    e0d = (fr[0] - c0 * Gd) * rF;
  }

  // ---- eliminate LAST -> 128-ring tridiagonal in FIRST ----
  v2 pa, pg, pd;
  {
    v2 e1aP = seamL(e1a, lane, 1);
    v2 e1gP = seamL(e1g, lane, 1);
    v2 e1dP = seamL(e1d, lane, 1);
    // pos 0: e0a == 0 exactly (masked), so the zeroed prev values are inert.
    v2 T = rcp2(bc(1.f) - e0a * e1gP - e0g * e1a);
    pa = -(e0a * e1aP) * T;
    pg = -(e0g * e1g) * T;
    pd = (e0d - e0a * e1dP - e0g * e1d) * T;
  }

  // ---- PCR over the 128-ring: 6 shuffle steps + 1 component-swap step ----
  #pragma unroll
  for (int st = 1; st <= 32; st <<= 1) {
    v2 La = seamL(pa, lane, st), Lg = seamL(pg, lane, st), Ld = seamL(pd, lane, st);
    v2 Ra = seamR(pa, lane, st), Rg = seamR(pg, lane, st), Rd = seamR(pd, lane, st);
    v2 r   = rcp2(bc(1.f) - pa * Lg - pg * Ra);
    v2 npa = -(pa * La) * r;
    v2 npg = -(pg * Rg) * r;
    v2 npd = (pd - pa * Ld - pg * Rd) * r;
    pa = npa; pg = npg; pd = npd;
  }
  {
    // st = 64: left/right neighbors are the other component of the same lane.
    v2 La = (v2){0.f, pa.x}, Lg = (v2){0.f, pg.x}, Ld = (v2){0.f, pd.x};
    v2 Ra = (v2){pa.y, 0.f}, Rg = (v2){pg.y, 0.f}, Rd = (v2){pd.y, 0.f};
    v2 r   = rcp2(bc(1.f) - pa * Lg - pg * Ra);
    v2 npd = (pd - pa * Ld - pg * Rd) * r;
    pd = npd;
  }

  // ---- recover LAST; endpoints of interiors from final sweep states ----
  v2 Fv = pd;                        // x0 of own blocks
  v2 Fn = seamR(Fv, lane, 1);        // x0 of next block (pos 127: e1g==0)
  v2 Lv = e1d - e1a * Fv - e1g * Fn; // x7 of own blocks

  v2 x1 = Gd + Hd * Fv + Kd * Lv;
  v2 x6 = Gu + Hu * Lv + Ku * Fv;

  // ---- reconstruct x2,x3 (up) and x5,x4 (down) via raw recurrences ----
  v2 x2, x3, x4, x5;
  {
    v2 al1, ga1, al2, ga2, al3, ga3;
    edgeAG(e0base + bc(dv),        al1, ga1);   // edge 1
    edgeAG(e0base + bc(2.f * dv),  al2, ga2);   // edge 2
    edgeAG(e0base + bc(3.f * dv),  al3, ga3);   // edge 3
    // row1: x2 = (f1 - a1*x0 - b1*x1)/c1
    v2 b1 = bc(1.f) - ga1 - al2;
    x2 = (fr[1] - al1 * Fv - b1 * x1) * rcp2(ga2);
    // row2: x3 = (f2 - a2*x1 - b2*x2)/c2
    v2 b2 = bc(1.f) - ga2 - al3;
    x3 = (fr[2] - al2 * x1 - b2 * x2) * rcp2(ga3);

    v2 al5, ga5, al6, ga6, al7, ga7;
    edgeAG(e0base + bc(5.f * dv),  al5, ga5);   // edge 5
    edgeAG(e0base + bc(6.f * dv),  al6, ga6);   // edge 6
    edgeAG(e0base + bc(7.f * dv),  al7, ga7);   // edge 7
    // row6: x5 = (f6 - b6*x6 - c6*x7)/a6
    v2 b6 = bc(1.f) - ga6 - al7;
    x5 = (fr[6] - b6 * x6 - ga7 * Lv) * rcp2(al6);
    // row5: x4 = (f5 - b5*x5 - c5*x6)/a5
    v2 b5 = bc(1.f) - ga5 - al6;
    x4 = (fr[5] - b5 * x5 - ga6 * x6) * rcp2(al5);
  }

  float* op = out + (size_t)row * NVELL + cb;
  reinterpret_cast<float4*>(op)[0]       = make_float4(Fv.x, x1.x, x2.x, x3.x);
  reinterpret_cast<float4*>(op)[1]       = make_float4(x4.x, x5.x, x6.x, Lv.x);
  reinterpret_cast<float4*>(op + 512)[0] = make_float4(Fv.y, x1.y, x2.y, x3.y);
  reinterpret_cast<float4*>(op + 512)[1] = make_float4(x4.y, x5.y, x6.y, Lv.y);
}

extern "C" void kernel_launch(void* const* d_in, const int* in_sizes, int n_in,
                              void* d_out, int out_size, void* d_ws, size_t ws_size,
                              hipStream_t stream) {
  const float* f   = (const float*)d_in[0];
  const float* v   = (const float*)d_in[1];
  const float* ve  = (const float*)d_in[2];
  const float* dvp = (const float*)d_in[3];
  const float* nup = (const float*)d_in[4];
  const float* dtp = (const float*)d_in[5];
  float* out = (float*)d_out;
  int nrows  = in_sizes[0] / NVELL;
  int blocks = (nrows + 3) / 4;
  hipLaunchKernelGGL(fp_step_kernel, dim3(blocks), dim3(256), 0, stream,
                     f, v, ve, dvp, nup, dtp, out, nrows);
}